// Round 2
// baseline (285.365 us; speedup 1.0000x reference)
//
#include <hip/hip_runtime.h>
#include <hip/hip_bf16.h>

#define B_ 2
#define S_ 2048
#define D_ 1024
#define H_ 16
#define DK_ 64
#define M_ (B_*S_)          // 4096 token rows

typedef __bf16 bf16;
typedef __bf16 bf16x8 __attribute__((ext_vector_type(8)));
typedef __bf16 bf16x4 __attribute__((ext_vector_type(4)));
typedef float  f32x4  __attribute__((ext_vector_type(4)));

#define GLOAD_LDS16(gp, lp) __builtin_amdgcn_global_load_lds( \
    (const __attribute__((address_space(1))) void*)(gp),      \
    (__attribute__((address_space(3))) void*)(lp), 16, 0, 0)

// ---------------- fp32 -> bf16 cast (vectorized x8) ----------------
__global__ __launch_bounds__(256) void cast_kernel(
    const float* __restrict__ q, const float* __restrict__ k, const float* __restrict__ v,
    const float* __restrict__ wq, const float* __restrict__ wk,
    const float* __restrict__ wv, const float* __restrict__ wo,
    bf16* __restrict__ dst)
{
  const size_t XN = (size_t)M_ * D_;   // 4Mi
  const size_t WN = (size_t)D_ * D_;   // 1Mi
  size_t e = ((size_t)blockIdx.x * 256 + threadIdx.x) * 8;
  const float* src; size_t off;
  if (e < XN)        { src = q; off = e; }
  else if (e < 2*XN) { src = k; off = e - XN; }
  else if (e < 3*XN) { src = v; off = e - 2*XN; }
  else {
    size_t w = e - 3*XN; size_t wi = w >> 20; off = w & (WN - 1);
    src = (wi == 0) ? wq : (wi == 1) ? wk : (wi == 2) ? wv : wo;
  }
  float4 a = *reinterpret_cast<const float4*>(src + off);
  float4 b = *reinterpret_cast<const float4*>(src + off + 4);
  bf16x8 o;
  o[0]=(bf16)a.x; o[1]=(bf16)a.y; o[2]=(bf16)a.z; o[3]=(bf16)a.w;
  o[4]=(bf16)b.x; o[5]=(bf16)b.y; o[6]=(bf16)b.z; o[7]=(bf16)b.w;
  *reinterpret_cast<bf16x8*>(dst + e) = o;
}

// ---------------- shared NT-GEMM mainloop: C = A(MxK) * W(NxK)^T ----------------
// 128x128 tile, BK=32, 4 waves (2x2), acc 4x4 of 16x16 fragments per wave.
__device__ __forceinline__ void gemm_mainloop_128(
    const bf16* __restrict__ A, const bf16* __restrict__ W,
    int m0, int n0, int Kdim, bf16* As, bf16* Bs, f32x4 acc[4][4])
{
  const int tid  = threadIdx.x;
  const int lane = tid & 63;
  const int wave = tid >> 6;
  const int wr   = wave >> 1;
  const int wc   = wave & 1;
  const int g    = lane >> 4;
  const int c    = lane & 15;

#pragma unroll
  for (int i = 0; i < 4; ++i)
#pragma unroll
    for (int j = 0; j < 4; ++j)
      acc[i][j] = (f32x4){0.f, 0.f, 0.f, 0.f};

  for (int kt = 0; kt < Kdim; kt += 32) {
    __syncthreads();
#pragma unroll
    for (int u = 0; u < 2; ++u) {
      int ch  = tid + u*256;          // 16B chunk id, 512 per tile
      int row = ch >> 2;              // 4 chunks per 64B row
      int col = (ch & 3) * 8;         // elements
      GLOAD_LDS16(A + (size_t)(m0 + row)*Kdim + kt + col, As + ch*8);
      GLOAD_LDS16(W + (size_t)(n0 + row)*Kdim + kt + col, Bs + ch*8);
    }
    __syncthreads();

    bf16x8 af[4], bw[4];
#pragma unroll
    for (int i = 0; i < 4; ++i)
      af[i] = *reinterpret_cast<const bf16x8*>(As + (wr*64 + i*16 + c)*32 + g*8);
#pragma unroll
    for (int j = 0; j < 4; ++j)
      bw[j] = *reinterpret_cast<const bf16x8*>(Bs + (wc*64 + j*16 + c)*32 + g*8);
#pragma unroll
    for (int i = 0; i < 4; ++i)
#pragma unroll
      for (int j = 0; j < 4; ++j)
        acc[i][j] = __builtin_amdgcn_mfma_f32_16x16x32_bf16(af[i], bw[j], acc[i][j], 0, 0, 0);
  }
}

// ---------------- QKV projection; writes Q,K as [B,H,S,DK], V as [B,H,DK,S] ----------------
__global__ __launch_bounds__(256) void gemm_qkv_kernel(
    const bf16* __restrict__ X, const bf16* __restrict__ Wb,
    const float* __restrict__ bq, const float* __restrict__ bk, const float* __restrict__ bv,
    bf16* __restrict__ Qo, bf16* __restrict__ Ko, bf16* __restrict__ Vo)
{
  __shared__ bf16 As[128*32];
  __shared__ bf16 Bs[128*32];
  const int z  = blockIdx.z;
  const int m0 = blockIdx.y * 128;
  const int n0 = blockIdx.x * 128;
  const bf16* A = X  + (size_t)z * ((size_t)M_ * D_);
  const bf16* W = Wb + (size_t)z * ((size_t)D_ * D_);
  const float* bias = (z == 0) ? bq : (z == 1) ? bk : bv;

  f32x4 acc[4][4];
  gemm_mainloop_128(A, W, m0, n0, D_, As, Bs, acc);

  const int lane = threadIdx.x & 63;
  const int wave = threadIdx.x >> 6;
  const int wr = wave >> 1, wc = wave & 1;
  const int g = lane >> 4,  c = lane & 15;
  bf16* dstQK = (z == 0) ? Qo : Ko;

#pragma unroll
  for (int i = 0; i < 4; ++i) {
#pragma unroll
    for (int j = 0; j < 4; ++j) {
      const int n  = n0 + wc*64 + j*16 + c;
      const float bn = bias[n];
      const int h = n >> 6, dk = n & 63;
      const int mrow = m0 + wr*64 + i*16 + g*4;     // 4 consecutive m
      if (z == 2) {
        const int b = mrow >> 11, s = mrow & 2047;  // 4 consecutive s, no b crossing
        bf16x4 pv;
#pragma unroll
        for (int r = 0; r < 4; ++r) pv[r] = (bf16)(acc[i][j][r] + bn);
        *reinterpret_cast<bf16x4*>(Vo + ((size_t)((b*H_ + h)*DK_ + dk))*S_ + s) = pv;
      } else {
#pragma unroll
        for (int r = 0; r < 4; ++r) {
          const int m = mrow + r;
          const int b = m >> 11, s = m & 2047;
          dstQK[((size_t)((b*H_ + h)*S_ + s))*DK_ + dk] = (bf16)(acc[i][j][r] + bn);
        }
      }
    }
  }
}

// ---------------- output projection: fp32 out + bias ----------------
__global__ __launch_bounds__(256) void gemm_out_kernel(
    const bf16* __restrict__ A, const bf16* __restrict__ W,
    const float* __restrict__ bias, float* __restrict__ out)
{
  __shared__ bf16 As[128*32];
  __shared__ bf16 Bs[128*32];
  const int m0 = blockIdx.y * 128;
  const int n0 = blockIdx.x * 128;

  f32x4 acc[4][4];
  gemm_mainloop_128(A, W, m0, n0, D_, As, Bs, acc);

  const int lane = threadIdx.x & 63;
  const int wave = threadIdx.x >> 6;
  const int wr = wave >> 1, wc = wave & 1;
  const int g = lane >> 4,  c = lane & 15;

#pragma unroll
  for (int i = 0; i < 4; ++i) {
#pragma unroll
    for (int j = 0; j < 4; ++j) {
      const int n = n0 + wc*64 + j*16 + c;
      const float bn = bias[n];
      const int mrow = m0 + wr*64 + i*16 + g*4;
#pragma unroll
      for (int r = 0; r < 4; ++r)
        out[(size_t)(mrow + r)*D_ + n] = acc[i][j][r] + bn;
    }
  }
}

// ---------------- causal flash attention ----------------
// Block: 128 q-rows (4 waves x 32), KV tiles of 64. Swapped QK^T (mfma(K,Q)).
// K/V/P LDS XOR-swizzled byte^=(row&7)<<4; K/V via pre-swizzled global_load_lds source.
__global__ __launch_bounds__(256) void attn_kernel(
    const bf16* __restrict__ Q, const bf16* __restrict__ K,
    const bf16* __restrict__ Vt, bf16* __restrict__ O)
{
  const int qt   = (int)gridDim.x - 1 - (int)blockIdx.x;  // big blocks dispatch first
  const int bh   = blockIdx.y;
  const int b    = bh >> 4;
  const int hh   = bh & 15;
  const int q0   = qt * 128;
  const int tid  = threadIdx.x;
  const int wave = tid >> 6;
  const int lane = tid & 63;
  const int g    = lane >> 4;
  const int c    = lane & 15;

  __shared__ bf16 Kt_lds[64*64];        // [kv][d], swizzled
  __shared__ bf16 Vt_lds[64*64];        // [dk][kv], swizzled
  __shared__ bf16 P_lds[4][32*64];      // per-wave [q][kv], swizzled

  const bf16* Qh = Q  + (size_t)bh * (S_*DK_);
  const bf16* Kh = K  + (size_t)bh * (S_*DK_);
  const bf16* Vh = Vt + (size_t)bh * (DK_*S_);

  const int qw0 = q0 + wave*32;

  // Q fragments (B-operand of swapped QK^T): [qf][d-chunk]
  bf16x8 qfrag[2][2];
#pragma unroll
  for (int qf = 0; qf < 2; ++qf)
#pragma unroll
    for (int ch = 0; ch < 2; ++ch)
      qfrag[qf][ch] = *reinterpret_cast<const bf16x8*>(
          Qh + (size_t)(qw0 + qf*16 + c)*DK_ + ch*32 + g*8);

  f32x4 o_[2][4];
#pragma unroll
  for (int qf = 0; qf < 2; ++qf)
#pragma unroll
    for (int d = 0; d < 4; ++d)
      o_[qf][d] = (f32x4){0.f, 0.f, 0.f, 0.f};
  float m_st[2] = {-1e30f, -1e30f};
  float l_st[2] = {0.f, 0.f};

  const float SC = 0.18033688011112042f;  // (1/sqrt(64)) * log2(e) -> exp2 domain

  const int ntiles = q0/64 + 2;
  const int qmaxw  = qw0 + 31;

  for (int t = 0; t < ntiles; ++t) {
    const int kv0 = t * 64;
    __syncthreads();
#pragma unroll
    for (int u = 0; u < 2; ++u) {
      int ch  = tid + u*256;            // 16B chunk, 512 per 8KB tile
      int row = ch >> 3;                // 8 chunks per 128B row
      int ssl = (ch & 7) ^ (row & 7);   // pre-swizzled source slot (rule #21)
      GLOAD_LDS16(Kh + (size_t)(kv0 + row)*DK_ + ssl*8, Kt_lds + ch*8);
      GLOAD_LDS16(Vh + (size_t)row*S_ + kv0 + ssl*8,    Vt_lds + ch*8);
    }
    __syncthreads();

    if (kv0 <= qmaxw) {
      // S^T = K * Q^T : st[kvf][qf], lane holds ST[kv0+kvf*16+g*4+r][qw0+qf*16+c]
      f32x4 st[4][2];
#pragma unroll
      for (int kvf = 0; kvf < 4; ++kvf)
#pragma unroll
        for (int qf = 0; qf < 2; ++qf)
          st[kvf][qf] = (f32x4){0.f, 0.f, 0.f, 0.f};

#pragma unroll
      for (int kvf = 0; kvf < 4; ++kvf) {
        const int kvr = kvf*16 + c;
        bf16x8 kf[2];
#pragma unroll
        for (int ch = 0; ch < 2; ++ch) {
          int off = kvr*128 + (((ch*4 + g) ^ (kvr & 7)) << 4);
          kf[ch] = *reinterpret_cast<const bf16x8*>(
              reinterpret_cast<const char*>(Kt_lds) + off);
        }
#pragma unroll
        for (int qf = 0; qf < 2; ++qf)
#pragma unroll
          for (int ch = 0; ch < 2; ++ch)
            st[kvf][qf] = __builtin_amdgcn_mfma_f32_16x16x32_bf16(
                kf[ch], qfrag[qf][ch], st[kvf][qf], 0, 0, 0);
      }

      // online softmax (exp2 domain), P -> per-wave LDS (packed b64, swizzled)
#pragma unroll
      for (int qf = 0; qf < 2; ++qf) {
        const int qrow = qw0 + qf*16 + c;
        float mloc = -1e30f;
#pragma unroll
        for (int kvf = 0; kvf < 4; ++kvf)
#pragma unroll
          for (int r = 0; r < 4; ++r) {
            const int kv = kv0 + kvf*16 + g*4 + r;
            float vv = st[kvf][qf][r] * SC;
            vv = (kv <= qrow) ? vv : -1e30f;   // causal
            st[kvf][qf][r] = vv;
            mloc = fmaxf(mloc, vv);
          }
        mloc = fmaxf(mloc, __shfl_xor(mloc, 16));
        mloc = fmaxf(mloc, __shfl_xor(mloc, 32));
        const float mnew = fmaxf(m_st[qf], mloc);
        const float corr = exp2f(m_st[qf] - mnew);
        float lsum = 0.f;
        const int q_l = qf*16 + c;
#pragma unroll
        for (int kvf = 0; kvf < 4; ++kvf) {
          bf16x4 pb;
#pragma unroll
          for (int r = 0; r < 4; ++r) {
            float p = exp2f(st[kvf][qf][r] - mnew);
            lsum += p;
            pb[r] = (bf16)p;
          }
          int wb = (q_l*128 + kvf*32 + g*8) ^ ((q_l & 7) << 4);
          *reinterpret_cast<bf16x4*>(reinterpret_cast<char*>(P_lds[wave]) + wb) = pb;
        }
        lsum += __shfl_xor(lsum, 16);
        lsum += __shfl_xor(lsum, 32);
        l_st[qf] = l_st[qf]*corr + lsum;
        m_st[qf] = mnew;
        // rescale O: O-rows are g*4+r, stats live at lanes with c==g*4+r
#pragma unroll
        for (int r = 0; r < 4; ++r) {
          float rc = __shfl(corr, (lane & 48) | (g*4 + r));
#pragma unroll
          for (int d = 0; d < 4; ++d)
            o_[qf][d][r] *= rc;
        }
      }

      // O += P * V  (A = P from LDS, B = V^T rows)
      bf16x8 pf[2][2];
#pragma unroll
      for (int qf = 0; qf < 2; ++qf) {
        const int q_l = qf*16 + c;
#pragma unroll
        for (int ch = 0; ch < 2; ++ch) {
          int rb = (q_l*128 + ch*64 + g*16) ^ ((q_l & 7) << 4);
          pf[qf][ch] = *reinterpret_cast<const bf16x8*>(
              reinterpret_cast<const char*>(P_lds[wave]) + rb);
        }
      }
#pragma unroll
      for (int d = 0; d < 4; ++d) {
        const int dkr = d*16 + c;
#pragma unroll
        for (int ch = 0; ch < 2; ++ch) {
          int vb = dkr*128 + (((ch*4 + g) ^ (dkr & 7)) << 4);
          bf16x8 vf = *reinterpret_cast<const bf16x8*>(
              reinterpret_cast<const char*>(Vt_lds) + vb);
#pragma unroll
          for (int qf = 0; qf < 2; ++qf)
            o_[qf][d] = __builtin_amdgcn_mfma_f32_16x16x32_bf16(
                pf[qf][ch], vf, o_[qf][d], 0, 0, 0);
        }
      }
    }
  }

  // epilogue: O /= l, store [B,S,H,DK] bf16
#pragma unroll
  for (int qf = 0; qf < 2; ++qf) {
    const float linv = 1.f / l_st[qf];
#pragma unroll
    for (int r = 0; r < 4; ++r) {
      const float li = __shfl(linv, (lane & 48) | (g*4 + r));
      const int qrow = qw0 + qf*16 + g*4 + r;
      bf16* orow = O + ((size_t)(b*S_ + qrow)*H_ + hh)*DK_;
#pragma unroll
      for (int d = 0; d < 4; ++d)
        orow[d*16 + c] = (bf16)(o_[qf][d][r] * li);
    }
  }
}

// ---------------- launch ----------------
extern "C" void kernel_launch(void* const* d_in, const int* in_sizes, int n_in,
                              void* d_out, int out_size, void* d_ws, size_t ws_size,
                              hipStream_t stream)
{
  const float* q    = (const float*)d_in[0];
  const float* k    = (const float*)d_in[1];
  const float* v    = (const float*)d_in[2];
  // d_in[3] = mask (causal tril; implemented analytically)
  const float* wq_w = (const float*)d_in[4];
  const float* wq_b = (const float*)d_in[5];
  const float* wk_w = (const float*)d_in[6];
  const float* wk_b = (const float*)d_in[7];
  const float* wv_w = (const float*)d_in[8];
  const float* wv_b = (const float*)d_in[9];
  const float* wo_w = (const float*)d_in[10];
  const float* wo_b = (const float*)d_in[11];

  const size_t XN = (size_t)M_ * D_;   // 4Mi elems
  const size_t WN = (size_t)D_ * D_;   // 1Mi elems
  bf16* ws  = (bf16*)d_ws;
  bf16* xq  = ws;                // 3*XN: xq,xk,xv bf16
  bf16* wqb = ws + 3*XN;         // 4*WN: wq,wk,wv,wo bf16
  bf16* Qs  = wqb + 4*WN;        // XN  [B,H,S,DK]
  bf16* Ks  = Qs + XN;           // XN  [B,H,S,DK]
  bf16* Vts = Ks + XN;           // XN  [B,H,DK,S]
  bf16* Os  = ws;                // XN  [B,S,H,DK] — reuses xq (dead after proj GEMM)

  cast_kernel<<<dim3(8192), dim3(256), 0, stream>>>(q, k, v, wq_w, wk_w, wv_w, wo_w, xq);
  gemm_qkv_kernel<<<dim3(8, 32, 3), dim3(256), 0, stream>>>(
      xq, wqb, wq_b, wk_b, wv_b, Qs, Ks, Vts);
  attn_kernel<<<dim3(16, 32), dim3(256), 0, stream>>>(Qs, Ks, Vts, Os);
  gemm_out_kernel<<<dim3(8, 32), dim3(256), 0, stream>>>(Os, wqb + 3*WN, wo_b, (float*)d_out);
}

// Round 8
// 267.657 us; speedup vs baseline: 1.0662x; 1.0662x over previous
//
#include <hip/hip_runtime.h>
#include <hip/hip_bf16.h>

#define B_ 2
#define S_ 2048
#define D_ 1024
#define H_ 16
#define DK_ 64
#define M_ (B_*S_)          // 4096 token rows

typedef __bf16 bf16;
typedef __bf16 bf16x8 __attribute__((ext_vector_type(8)));
typedef __bf16 bf16x4 __attribute__((ext_vector_type(4)));
typedef __bf16 bf16x2 __attribute__((ext_vector_type(2)));
typedef float  f32x4  __attribute__((ext_vector_type(4)));
typedef float  f32x16 __attribute__((ext_vector_type(16)));
typedef int    i32x4  __attribute__((ext_vector_type(4)));

#define GLOAD_LDS16(gp, lp) __builtin_amdgcn_global_load_lds( \
    (const __attribute__((address_space(1))) void*)(gp),      \
    (__attribute__((address_space(3))) void*)(lp), 16, 0, 0)

// pack two f32 -> one u32 of 2 bf16 (pure C++, no asm)
static __device__ __forceinline__ int packbf(float a, float b) {
  bf16x2 t; t[0] = (bf16)a; t[1] = (bf16)b;
  return __builtin_bit_cast(int, t);
}

// ---------------- fp32 -> bf16 cast (vectorized x8) ----------------
__global__ __launch_bounds__(256) void cast_kernel(
    const float* __restrict__ q, const float* __restrict__ k, const float* __restrict__ v,
    const float* __restrict__ wq, const float* __restrict__ wk,
    const float* __restrict__ wv, const float* __restrict__ wo,
    bf16* __restrict__ dst)
{
  const size_t XN = (size_t)M_ * D_;   // 4Mi
  const size_t WN = (size_t)D_ * D_;   // 1Mi
  size_t e = ((size_t)blockIdx.x * 256 + threadIdx.x) * 8;
  const float* src; size_t off;
  if (e < XN)        { src = q; off = e; }
  else if (e < 2*XN) { src = k; off = e - XN; }
  else if (e < 3*XN) { src = v; off = e - 2*XN; }
  else {
    size_t w = e - 3*XN; size_t wi = w >> 20; off = w & (WN - 1);
    src = (wi == 0) ? wq : (wi == 1) ? wk : (wi == 2) ? wv : wo;
  }
  float4 a = *reinterpret_cast<const float4*>(src + off);
  float4 b = *reinterpret_cast<const float4*>(src + off + 4);
  bf16x8 o;
  o[0]=(bf16)a.x; o[1]=(bf16)a.y; o[2]=(bf16)a.z; o[3]=(bf16)a.w;
  o[4]=(bf16)b.x; o[5]=(bf16)b.y; o[6]=(bf16)b.z; o[7]=(bf16)b.w;
  *reinterpret_cast<bf16x8*>(dst + e) = o;
}

// ---------------- shared NT-GEMM mainloop: C = A(MxK) * W(NxK)^T ----------------
__device__ __forceinline__ void gemm_mainloop_128(
    const bf16* __restrict__ A, const bf16* __restrict__ W,
    int m0, int n0, int Kdim, bf16* As, bf16* Bs, f32x4 acc[4][4])
{
  const int tid  = threadIdx.x;
  const int lane = tid & 63;
  const int wave = tid >> 6;
  const int wr   = wave >> 1;
  const int wc   = wave & 1;
  const int g    = lane >> 4;
  const int c    = lane & 15;

#pragma unroll
  for (int i = 0; i < 4; ++i)
#pragma unroll
    for (int j = 0; j < 4; ++j)
      acc[i][j] = (f32x4){0.f, 0.f, 0.f, 0.f};

  for (int kt = 0; kt < Kdim; kt += 32) {
    __syncthreads();
#pragma unroll
    for (int u = 0; u < 2; ++u) {
      int ch  = tid + u*256;          // 16B chunk id, 512 per tile
      int row = ch >> 2;              // 4 chunks per 64B row
      int col = (ch & 3) * 8;         // elements
      GLOAD_LDS16(A + (size_t)(m0 + row)*Kdim + kt + col, As + ch*8);
      GLOAD_LDS16(W + (size_t)(n0 + row)*Kdim + kt + col, Bs + ch*8);
    }
    __syncthreads();

    bf16x8 af[4], bw[4];
#pragma unroll
    for (int i = 0; i < 4; ++i)
      af[i] = *reinterpret_cast<const bf16x8*>(As + (wr*64 + i*16 + c)*32 + g*8);
#pragma unroll
    for (int j = 0; j < 4; ++j)
      bw[j] = *reinterpret_cast<const bf16x8*>(Bs + (wc*64 + j*16 + c)*32 + g*8);
#pragma unroll
    for (int i = 0; i < 4; ++i)
#pragma unroll
      for (int j = 0; j < 4; ++j)
        acc[i][j] = __builtin_amdgcn_mfma_f32_16x16x32_bf16(af[i], bw[j], acc[i][j], 0, 0, 0);
  }
}

// ---------------- QKV projection; Q,K -> [B,H,S,DK] (Q pre-scaled), V -> [B,H,DK,S] ----------------
__global__ __launch_bounds__(256) void gemm_qkv_kernel(
    const bf16* __restrict__ X, const bf16* __restrict__ Wb,
    const float* __restrict__ bq, const float* __restrict__ bk, const float* __restrict__ bv,
    bf16* __restrict__ Qo, bf16* __restrict__ Ko, bf16* __restrict__ Vo)
{
  __shared__ bf16 As[128*32];
  __shared__ bf16 Bs[128*32];
  const int z  = blockIdx.z;
  const int m0 = blockIdx.y * 128;
  const int n0 = blockIdx.x * 128;
  const bf16* A = X  + (size_t)z * ((size_t)M_ * D_);
  const bf16* W = Wb + (size_t)z * ((size_t)D_ * D_);
  const float* bias = (z == 0) ? bq : (z == 1) ? bk : bv;
  // fold (1/sqrt(DK))*log2(e) into Q so attention softmax runs in exp2 domain
  const float sc = (z == 0) ? 0.18033688011112042f : 1.0f;

  f32x4 acc[4][4];
  gemm_mainloop_128(A, W, m0, n0, D_, As, Bs, acc);

  const int lane = threadIdx.x & 63;
  const int wave = threadIdx.x >> 6;
  const int wr = wave >> 1, wc = wave & 1;
  const int g = lane >> 4,  c = lane & 15;
  bf16* dstQK = (z == 0) ? Qo : Ko;

#pragma unroll
  for (int i = 0; i < 4; ++i) {
#pragma unroll
    for (int j = 0; j < 4; ++j) {
      const int n  = n0 + wc*64 + j*16 + c;
      const float bn = bias[n];
      const int h = n >> 6, dk = n & 63;
      const int mrow = m0 + wr*64 + i*16 + g*4;     // 4 consecutive m
      if (z == 2) {
        const int b = mrow >> 11, s = mrow & 2047;  // 4 consecutive s, no b crossing
        bf16x4 pv;
#pragma unroll
        for (int r = 0; r < 4; ++r) pv[r] = (bf16)(acc[i][j][r] + bn);
        *reinterpret_cast<bf16x4*>(Vo + ((size_t)((b*H_ + h)*DK_ + dk))*S_ + s) = pv;
      } else {
#pragma unroll
        for (int r = 0; r < 4; ++r) {
          const int m = mrow + r;
          const int b = m >> 11, s = m & 2047;
          dstQK[((size_t)((b*H_ + h)*S_ + s))*DK_ + dk] = (bf16)((acc[i][j][r] + bn) * sc);
        }
      }
    }
  }
}

// ---------------- output projection: fp32 out + bias ----------------
__global__ __launch_bounds__(256) void gemm_out_kernel(
    const bf16* __restrict__ A, const bf16* __restrict__ W,
    const float* __restrict__ bias, float* __restrict__ out)
{
  __shared__ bf16 As[128*32];
  __shared__ bf16 Bs[128*32];
  const int m0 = blockIdx.y * 128;
  const int n0 = blockIdx.x * 128;

  f32x4 acc[4][4];
  gemm_mainloop_128(A, W, m0, n0, D_, As, Bs, acc);

  const int lane = threadIdx.x & 63;
  const int wave = threadIdx.x >> 6;
  const int wr = wave >> 1, wc = wave & 1;
  const int g = lane >> 4,  c = lane & 15;

#pragma unroll
  for (int i = 0; i < 4; ++i) {
#pragma unroll
    for (int j = 0; j < 4; ++j) {
      const int n = n0 + wc*64 + j*16 + c;
      const float bn = bias[n];
      const int mrow = m0 + wr*64 + i*16 + g*4;
#pragma unroll
      for (int r = 0; r < 4; ++r)
        out[(size_t)(mrow + r)*D_ + n] = acc[i][j][r] + bn;
    }
  }
}

// ---------------- causal flash attention, 32x32 MFMA, in-register softmax ----------------
// 4 waves x 32 q-rows = 128 q/block. KV tiles of 64, double-buffered LDS.
// Swapped QK^T (S^T = K*Q^T): q = lane&31 lane-local. P never touches LDS.
// ZERO inline asm this round (bisect): all cross-half exchange via __shfl_xor(.,32)
// (the R2-proven primitive). pa B-operand built with shfl + select.
// Bounded numerics: m_ >= 0, sentinel -30000 (exp2 -> exact 0), corr in (0,1].
__global__ __launch_bounds__(256, 2) void attn_kernel(
    const bf16* __restrict__ Q, const bf16* __restrict__ K,
    const bf16* __restrict__ Vt, bf16* __restrict__ O)
{
  const int qt   = (int)gridDim.x - 1 - (int)blockIdx.x;  // big blocks dispatch first
  const int bh   = blockIdx.y;
  const int b    = bh >> 4;
  const int hh   = bh & 15;
  const int q0   = qt * 128;
  const int tid  = threadIdx.x;
  const int wave = tid >> 6;
  const int lane = tid & 63;
  const int ql   = lane & 31;
  const int hi   = lane >> 5;

  const float NEG = -30000.0f;    // masked-score sentinel; exp2f(<= -30000) == 0 exactly

  __shared__ bf16 Kl[2][64*64];   // [kv][d] rows of 128B, slot-swizzled
  __shared__ bf16 Vl[2][64*64];   // [dk][kv] rows of 128B, slot-swizzled

  const bf16* Qh = Q  + (size_t)bh * (S_*DK_);
  const bf16* Kh = K  + (size_t)bh * (S_*DK_);
  const bf16* Vh = Vt + (size_t)bh * (DK_*S_);

  const int qw0  = q0 + wave*32;
  const int qrow = qw0 + ql;

  // Q as B-operand of S^T = K*Q^T: lane(q=ql,hi) holds Q[qrow][ck*16 + hi*8 + j]
  bf16x8 qf[4];
#pragma unroll
  for (int ck = 0; ck < 4; ++ck)
    qf[ck] = *reinterpret_cast<const bf16x8*>(Qh + (size_t)qrow*DK_ + ck*16 + hi*8);

  f32x16 o0 = {}, o1 = {};        // O^T[dk][q]: col=q=ql, row=dk=(r&3)+8*(r>>2)+4*hi (+32 for o1)
  float m_ = 0.f, l_ = 0.f;       // m_ >= 0 invariant; exact running max above 0

  const int nt = q0/64 + 2;       // kv tiles covering [0, q0+128)

#define STAGE_KV(kv0s, bb) do {                                              \
  _Pragma("unroll")                                                          \
  for (int u = 0; u < 2; ++u) {                                              \
    int ch  = tid + u*256;                                                   \
    int row = ch >> 3;                                                       \
    int g   = (ch & 7) ^ (row & 7);   /* pre-swizzled source slot */         \
    GLOAD_LDS16(Kh + (size_t)((kv0s) + row)*DK_ + g*8, &Kl[bb][ch*8]);       \
    GLOAD_LDS16(Vh + (size_t)row*S_ + (kv0s) + g*8,    &Vl[bb][ch*8]);       \
  }                                                                          \
} while (0)

// build one PV B-operand fragment from 8 P values (pure shfl + select):
// hi=0 wants [own p0p1, own p2p3, partner p0p1, partner p2p3] of the LOW quad,
// hi=1 wants [partner p4p5, partner p6p7, own p4p5, own p6p7] of the HIGH quad.
#define MK_PA(dst, s, base) do {                                               \
    int x0 = packbf(s[(base)+0], s[(base)+1]);                                 \
    int x1 = packbf(s[(base)+2], s[(base)+3]);                                 \
    int y0 = packbf(s[(base)+4], s[(base)+5]);                                 \
    int y1 = packbf(s[(base)+6], s[(base)+7]);                                 \
    int px0 = __shfl_xor(x0, 32), px1 = __shfl_xor(x1, 32);                    \
    int py0 = __shfl_xor(y0, 32), py1 = __shfl_xor(y1, 32);                    \
    i32x4 w;                                                                   \
    w[0] = hi ? py0 : x0;  w[1] = hi ? py1 : x1;                               \
    w[2] = hi ? y0  : px0; w[3] = hi ? y1  : px1;                              \
    dst = __builtin_bit_cast(bf16x8, w);                                       \
  } while (0)

  int cur = 0;
  STAGE_KV(0, 0);
  __syncthreads();

  for (int t = 0; t < nt; ++t) {
    const int kv0 = t * 64;
    if (t + 1 < nt) STAGE_KV((t+1)*64, cur ^ 1);

    if (kv0 <= qw0 + 31) {
      const char* Kb = (const char*)Kl[cur];
      const char* Vb = (const char*)Vl[cur];

      // ---- S^T = K * Q^T : two 32x32 tiles (kv halves), K from LDS as A-op ----
      f32x16 st0 = {}, st1 = {};
#pragma unroll
      for (int ck = 0; ck < 4; ++ck) {
        bf16x8 kf0 = *reinterpret_cast<const bf16x8*>(
            Kb + ql*128 + (((ck*2 + hi) ^ (ql & 7)) << 4));
        st0 = __builtin_amdgcn_mfma_f32_32x32x16_bf16(kf0, qf[ck], st0, 0, 0, 0);
        bf16x8 kf1 = *reinterpret_cast<const bf16x8*>(
            Kb + (32 + ql)*128 + (((ck*2 + hi) ^ (ql & 7)) << 4));
        st1 = __builtin_amdgcn_mfma_f32_32x32x16_bf16(kf1, qf[ck], st1, 0, 0, 0);
      }

      // ---- causal mask: only diagonal tiles ----
      if (kv0 + 63 > qw0) {
#pragma unroll
        for (int r = 0; r < 16; ++r) {
          const int kvr = kv0 + (r & 3) + 8*(r >> 2) + 4*hi;
          st0[r] = (kvr      <= qrow) ? st0[r] : NEG;
          st1[r] = (kvr + 32 <= qrow) ? st1[r] : NEG;
        }
      }

      // ---- in-register online softmax, exact running max (q lane-local) ----
      float pm = st0[0];
#pragma unroll
      for (int r = 1; r < 16; ++r) pm = fmaxf(pm, st0[r]);
#pragma unroll
      for (int r = 0; r < 16; ++r) pm = fmaxf(pm, st1[r]);
      pm = fmaxf(pm, __shfl_xor(pm, 32));

      const float mnew = fmaxf(m_, pm);      // >= 0 always
      const float corr = exp2f(m_ - mnew);   // in (0,1]
      m_ = mnew;

      float ls = 0.f;
#pragma unroll
      for (int r = 0; r < 16; ++r) {
        float p = exp2f(st0[r] - mnew);   // <= 1; masked -> exact 0
        ls += p;
        st0[r] = p;
      }
#pragma unroll
      for (int r = 0; r < 16; ++r) {
        float p = exp2f(st1[r] - mnew);
        ls += p;
        st1[r] = p;
      }
      l_ = l_ * corr + (ls + __shfl_xor(ls, 32));
      o0 *= corr; o1 *= corr;

      // ---- P -> PV B-operand frags in registers (shfl + select, no asm) ----
      bf16x8 pa[4];
      MK_PA(pa[0], st0, 0);
      MK_PA(pa[1], st0, 8);
      MK_PA(pa[2], st1, 0);
      MK_PA(pa[3], st1, 8);

      // ---- O^T += V^T * P^T : V^T from LDS as A-op, P^T from regs as B-op ----
#pragma unroll
      for (int ck = 0; ck < 4; ++ck) {
        bf16x8 vf0 = *reinterpret_cast<const bf16x8*>(
            Vb + ql*128 + (((ck*2 + hi) ^ (ql & 7)) << 4));
        o0 = __builtin_amdgcn_mfma_f32_32x32x16_bf16(vf0, pa[ck], o0, 0, 0, 0);
        bf16x8 vf1 = *reinterpret_cast<const bf16x8*>(
            Vb + (32 + ql)*128 + (((ck*2 + hi) ^ (ql & 7)) << 4));
        o1 = __builtin_amdgcn_mfma_f32_32x32x16_bf16(vf1, pa[ck], o1, 0, 0, 0);
      }
    }

    __syncthreads();
    cur ^= 1;
  }

  // ---- epilogue: O /= l, store [B,S,H,DK] bf16 (q lane-local, dk in regs) ----
  const float linv = 1.0f / l_;
  bf16* orow = O + ((size_t)(b*S_ + qrow)*H_ + hh)*DK_;
#pragma unroll
  for (int w4 = 0; w4 < 4; ++w4) {
    bf16x4 s0, s1;
#pragma unroll
    for (int e = 0; e < 4; ++e) {
      s0[e] = (bf16)(o0[w4*4 + e] * linv);
      s1[e] = (bf16)(o1[w4*4 + e] * linv);
    }
    *reinterpret_cast<bf16x4*>(orow + 8*w4 + 4*hi)      = s0;   // dk = 8*w4+4*hi+e
    *reinterpret_cast<bf16x4*>(orow + 32 + 8*w4 + 4*hi) = s1;   // +32
  }
#undef STAGE_KV
#undef MK_PA
}

// ---------------- launch ----------------
extern "C" void kernel_launch(void* const* d_in, const int* in_sizes, int n_in,
                              void* d_out, int out_size, void* d_ws, size_t ws_size,
                              hipStream_t stream)
{
  const float* q    = (const float*)d_in[0];
  const float* k    = (const float*)d_in[1];
  const float* v    = (const float*)d_in[2];
  // d_in[3] = mask (causal tril; implemented analytically)
  const float* wq_w = (const float*)d_in[4];
  const float* wq_b = (const float*)d_in[5];
  const float* wk_w = (const float*)d_in[6];
  const float* wk_b = (const float*)d_in[7];
  const float* wv_w = (const float*)d_in[8];
  const float* wv_b = (const float*)d_in[9];
  const float* wo_w = (const float*)d_in[10];
  const float* wo_b = (const float*)d_in[11];

  const size_t XN = (size_t)M_ * D_;   // 4Mi elems
  const size_t WN = (size_t)D_ * D_;   // 1Mi elems
  bf16* ws  = (bf16*)d_ws;
  bf16* xq  = ws;                // 3*XN: xq,xk,xv bf16
  bf16* wqb = ws + 3*XN;         // 4*WN: wq,wk,wv,wo bf16
  bf16* Qs  = wqb + 4*WN;        // XN  [B,H,S,DK]  (pre-scaled)
  bf16* Ks  = Qs + XN;           // XN  [B,H,S,DK]
  bf16* Vts = Ks + XN;           // XN  [B,H,DK,S]
  bf16* Os  = ws;                // XN  [B,S,H,DK] — reuses xq (dead after proj GEMM)

  cast_kernel<<<dim3(8192), dim3(256), 0, stream>>>(q, k, v, wq_w, wk_w, wv_w, wo_w, xq);
  gemm_qkv_kernel<<<dim3(8, 32, 3), dim3(256), 0, stream>>>(
      xq, wqb, wq_b, wk_b, wv_b, Qs, Ks, Vts);
  attn_kernel<<<dim3(16, 32), dim3(256), 0, stream>>>(Qs, Ks, Vts, Os);
  gemm_out_kernel<<<dim3(8, 32), dim3(256), 0, stream>>>(Os, wqb + 3*WN, wo_b, (float*)d_out);
}